// Round 5
// baseline (76.038 us; speedup 1.0000x reference)
//
#include <hip/hip_runtime.h>
#include <hip/hip_bf16.h>

#define TT 2048
#define DD 128
#define NB 16
#define NTILE 32          // 64-key tiles per sequence
#define TILE_BYTES 16384  // 64x128 bf16

typedef __bf16 bf16x8 __attribute__((ext_vector_type(8)));
typedef __bf16 bf16x4 __attribute__((ext_vector_type(4)));
typedef float f32x4 __attribute__((ext_vector_type(4)));
typedef float f32x16 __attribute__((ext_vector_type(16)));

#define GLOAD_LDS16(g, l) __builtin_amdgcn_global_load_lds( \
    (const __attribute__((address_space(1))) void*)(g),     \
    (__attribute__((address_space(3))) void*)(l), 16, 0, 0)

__device__ __forceinline__ float warp16_sum(float v) {
    v += __shfl_xor(v, 1);
    v += __shfl_xor(v, 2);
    v += __shfl_xor(v, 4);
    v += __shfl_xor(v, 8);
    return v;
}
__device__ __forceinline__ float bf2f(unsigned int u16) {
    union { unsigned int i; float f; } x; x.i = u16 << 16; return x.f;
}
__device__ __forceinline__ unsigned int pk2(float lo, float hi) {
    unsigned short a = __builtin_bit_cast(unsigned short, (__bf16)lo);
    unsigned short b = __builtin_bit_cast(unsigned short, (__bf16)hi);
    return (unsigned int)a | ((unsigned int)b << 16);
}
__device__ __forceinline__ bf16x8 frag4(unsigned int a, unsigned int b,
                                        unsigned int c, unsigned int d) {
    uint4 u = make_uint4(a, b, c, d);
    return __builtin_bit_cast(bf16x8, u);
}
__device__ __forceinline__ f32x16 z16() {
    f32x16 v;
    #pragma unroll
    for (int i = 0; i < 16; ++i) v[i] = 0.f;
    return v;
}

// ---------------- prepass: K -> bf16 tiles, V -> bf16 transposed tiles ----------
// Tile-contiguous (16KB), PRE-SWIZZLED so linear global_load_lds lands swizzled.
// K tile byte(key,d) = key*256 + ((2d) ^ ((key&15)<<4))
// V tile byte(d,key) = (d>>1)*256 + (((d&1)*128 + 2*key) ^ (((d>>1)&15)<<4))
__global__ __launch_bounds__(256) void prepass(
    const float* __restrict__ K, const float* __restrict__ V,
    char* __restrict__ KB, char* __restrict__ VTB)
{
    const int t = blockIdx.x;
    const int b = blockIdx.y;
    const int tid = threadIdx.x;
    char* kdst = KB  + (size_t)(b * NTILE + t) * TILE_BYTES;
    char* vdst = VTB + (size_t)(b * NTILE + t) * TILE_BYTES;
    const float* kp = K + ((size_t)b * TT + t * 64) * DD;
    const float* vp = V + ((size_t)b * TT + t * 64) * DD;

    #pragma unroll
    for (int it = 0; it < 4; ++it) {
        int key = it * 16 + (tid >> 4);
        int d0  = (tid & 15) * 8;
        const float4* s = (const float4*)(kp + (size_t)key * DD + d0);
        float4 f0 = s[0], f1 = s[1];
        bf16x8 h;
        h[0]=(__bf16)f0.x; h[1]=(__bf16)f0.y; h[2]=(__bf16)f0.z; h[3]=(__bf16)f0.w;
        h[4]=(__bf16)f1.x; h[5]=(__bf16)f1.y; h[6]=(__bf16)f1.z; h[7]=(__bf16)f1.w;
        *(bf16x8*)(kdst + key * 256 + ((d0 * 2) ^ ((key & 15) << 4))) = h;
    }
    #pragma unroll
    for (int it = 0; it < 4; ++it) {
        int d  = tid & 127;
        int k0 = ((tid >> 7) + it * 2) * 8;
        bf16x8 h;
        #pragma unroll
        for (int j = 0; j < 8; ++j)
            h[j] = (__bf16)vp[(size_t)(k0 + j) * DD + d];
        *(bf16x8*)(vdst + (d >> 1) * 256 +
                   ((((d & 1) * 128) + 2 * k0) ^ (((d >> 1) & 15) << 4))) = h;
    }
}

// ---------------- main: 4 waves x 32 q-rows = 128 rows/block, 32x32x16 MFMA ----
// Swapped QK^T (A=K, B=Q): lane&31 = q, keys across regs -> softmax lane-local,
// P stays in registers (pack + shfl_xor(32) to build PV A-frags). No P LDS.
__global__ __launch_bounds__(256, 2) void attn_main(
    const float* __restrict__ Q,
    const char* __restrict__ KB, const char* __restrict__ VTB,
    float* __restrict__ O, char* __restrict__ SLOTS,
    int CHUNK, int NCMAX, int QBMIN)
{
    __shared__ __align__(16) unsigned short Klds[2][8192]; // 16KB each buf
    __shared__ __align__(16) unsigned short Vs[2][8192];

    const int b  = blockIdx.x;               // b on x: 2 seqs per XCD -> L2 fit
    const int qb = 15 - blockIdx.y;          // heavy q-blocks first
    const int ntile = 2 * qb + 2;
    const int nc = (ntile + CHUNK - 1) / CHUNK;
    if ((int)blockIdx.z >= nc) return;
    const int t0 = (int)(((long)blockIdx.z * ntile) / nc);       // balanced split
    const int t1 = (int)(((long)(blockIdx.z + 1) * ntile) / nc);

    const int tid  = threadIdx.x;
    const int lane = tid & 63;
    const int w    = tid >> 6;               // wave 0..3
    const int ln   = lane & 31;
    const int hi   = lane >> 5;
    const int qrow0 = qb * 128 + w * 32;     // wave's first q row
    const int q_abs = qrow0 + ln;            // this lane's q row

    const float SCALE = 0.08838834764831845f; // 1/sqrt(128)

    // ---- Q fragments (B-operand): Qf[kc][j] = Q[q_abs][kc*16 + 8*hi + j] ----
    const float* qrow = Q + ((size_t)b * TT + q_abs) * DD + 8 * hi;
    bf16x8 qf[8];
    #pragma unroll
    for (int kc = 0; kc < 8; ++kc) {
        float4 f0 = *(const float4*)(qrow + kc * 16);
        float4 f1 = *(const float4*)(qrow + kc * 16 + 4);
        bf16x8 t;
        t[0]=(__bf16)f0.x; t[1]=(__bf16)f0.y; t[2]=(__bf16)f0.z; t[3]=(__bf16)f0.w;
        t[4]=(__bf16)f1.x; t[5]=(__bf16)f1.y; t[6]=(__bf16)f1.z; t[7]=(__bf16)f1.w;
        qf[kc] = t;
    }

    f32x16 o[4];
    #pragma unroll
    for (int dg = 0; dg < 4; ++dg) o[dg] = z16();
    float lsum = 0.f;

    const char* kbase = KB  + (size_t)b * NTILE * TILE_BYTES;
    const char* vbase = VTB + (size_t)b * NTILE * TILE_BYTES;

    auto STAGE = [&](int t, int buf) {
        const char* ks = kbase + (size_t)t * TILE_BYTES;
        const char* vs = vbase + (size_t)t * TILE_BYTES;
        #pragma unroll
        for (int j = 0; j < 4; ++j) {
            int off = (w * 4 + j) * 1024 + lane * 16;
            GLOAD_LDS16(ks + off, (char*)Klds[buf] + off);
            GLOAD_LDS16(vs + off, (char*)Vs[buf]  + off);
        }
    };

    STAGE(t0, 0);
    int cur = 0;

    for (int t = t0; t < t1; ++t) {
        const int kb = t * 64;
        __syncthreads();                  // drains DMA + orders buffers

        if (t + 1 < t1) STAGE(t + 1, cur ^ 1);

        if (kb <= qrow0 + 31) {           // wave has unmasked rows in this tile
            const bool edge = (kb + 63 > qrow0);
            const char* kl = (const char*)Klds[cur];
            const char* vl = (const char*)Vs[cur];

            auto PROC = [&](int kg) {
                // ---- QK^T (swapped): S^T[key][q], two interleaved chains ----
                const int key = kg * 32 + ln;
                const int swk = (key & 15) << 4;
                const char* krow = kl + key * 256;
                f32x16 a0 = z16(), a1 = z16();
                #pragma unroll
                for (int kc = 0; kc < 8; kc += 2) {
                    bf16x8 kf0 = *(const bf16x8*)(krow + ((kc * 32 + 16 * hi) ^ swk));
                    bf16x8 kf1 = *(const bf16x8*)(krow + (((kc + 1) * 32 + 16 * hi) ^ swk));
                    a0 = __builtin_amdgcn_mfma_f32_32x32x16_bf16(kf0, qf[kc],     a0, 0, 0, 0);
                    a1 = __builtin_amdgcn_mfma_f32_32x32x16_bf16(kf1, qf[kc + 1], a1, 0, 0, 0);
                }
                // ---- exp (no-max softmax), mask on edge tiles ----
                float p[16];
                #pragma unroll
                for (int reg = 0; reg < 16; ++reg) {
                    int key_abs = kb + kg * 32 + (reg & 3) + 8 * (reg >> 2) + 4 * hi;
                    float pe = __expf((a0[reg] + a1[reg]) * SCALE);
                    if (edge && key_abs > q_abs) pe = 0.f;
                    p[reg] = pe;
                    lsum += pe;
                }
                // ---- build PV A-frags in registers (pack + cross-half swap) ----
                unsigned int wd[8], xr[8];
                #pragma unroll
                for (int i = 0; i < 8; ++i) wd[i] = pk2(p[2 * i], p[2 * i + 1]);
                #pragma unroll
                for (int i = 0; i < 8; ++i) xr[i] = __shfl_xor(wd[i], 32);
                bf16x8 pa0 = hi ? frag4(xr[2], xr[3], wd[2], wd[3])
                                : frag4(wd[0], wd[1], xr[0], xr[1]);
                bf16x8 pa1 = hi ? frag4(xr[6], xr[7], wd[6], wd[7])
                                : frag4(wd[4], wd[5], xr[4], xr[5]);
                // ---- PV: O[q][d] += P(32x32) * V(32x128) ----
                const int kc0 = 2 * kg;
                #pragma unroll
                for (int dg = 0; dg < 4; ++dg) {
                    int d = dg * 32 + ln;
                    const char* vrow = vl + (d >> 1) * 256;
                    int hv = (d & 1) * 128;
                    int swv = ((d >> 1) & 15) << 4;
                    bf16x8 vf0 = *(const bf16x8*)(vrow + ((hv + kc0 * 32 + 16 * hi) ^ swv));
                    bf16x8 vf1 = *(const bf16x8*)(vrow + ((hv + (kc0 + 1) * 32 + 16 * hi) ^ swv));
                    o[dg] = __builtin_amdgcn_mfma_f32_32x32x16_bf16(pa0, vf0, o[dg], 0, 0, 0);
                    o[dg] = __builtin_amdgcn_mfma_f32_32x32x16_bf16(pa1, vf1, o[dg], 0, 0, 0);
                }
            };

            PROC(0);
            if (kb + 32 <= qrow0 + 31) PROC(1);
        }
        cur ^= 1;
    }

    const float ltot = lsum + __shfl_xor(lsum, 32);   // full row-sum for q=ln

    if (t0 == 0 && t1 == ntile) {
        // ---- direct epilogue ----
        const float inv = 1.0f / ltot;
        float* op = O + ((size_t)b * TT + qrow0) * DD;
        #pragma unroll
        for (int reg = 0; reg < 16; ++reg) {
            int qr = (reg & 3) + 8 * (reg >> 2) + 4 * hi;
            float iv = __shfl(inv, qr);
            #pragma unroll
            for (int dg = 0; dg < 4; ++dg)
                op[(size_t)qr * DD + dg * 32 + ln] = o[dg][reg] * iv;
        }
    } else {
        // ---- partial epilogue: [128][128] bf16 raw sums + [128] fp32 l ----
        const int NQ = 16 - QBMIN;
        char* slot = SLOTS + (size_t)((b * NQ + (qb - QBMIN)) * NCMAX + blockIdx.z) * 33280;
        unsigned short* so = (unsigned short*)slot;
        float* sl = (float*)(slot + 32768);
        #pragma unroll
        for (int reg = 0; reg < 16; ++reg) {
            int row = w * 32 + (reg & 3) + 8 * (reg >> 2) + 4 * hi;
            #pragma unroll
            for (int dg = 0; dg < 4; ++dg)
                so[row * 128 + dg * 32 + ln] =
                    __builtin_bit_cast(unsigned short, (__bf16)o[dg][reg]);
        }
        if (hi == 0) sl[w * 32 + ln] = ltot;
    }
}

__global__ __launch_bounds__(256) void attn_combine(
    const char* __restrict__ SLOTS, float* __restrict__ O,
    int CHUNK, int NCMAX, int QBMIN)
{
    const int qb = QBMIN + blockIdx.x;
    const int b  = blockIdx.y;
    const int nc = (2 * qb + 2 + CHUNK - 1) / CHUNK;
    const int NQ = 16 - QBMIN;
    const int row  = threadIdx.x >> 1;
    const int half = (threadIdx.x & 1) * 64;
    const char* base = SLOTS + (size_t)((b * NQ + (qb - QBMIN)) * NCMAX) * 33280;

    float l = 0.f;
    for (int c = 0; c < nc; ++c)
        l += *(const float*)(base + (size_t)c * 33280 + 32768 + row * 4);
    float inv = 1.0f / l;

    float* op = O + ((size_t)b * TT + qb * 128 + row) * DD + half;
    #pragma unroll
    for (int g = 0; g < 8; ++g) {
        f32x4 a0 = (f32x4){0.f,0.f,0.f,0.f}, a1 = (f32x4){0.f,0.f,0.f,0.f};
        for (int c = 0; c < nc; ++c) {
            const uint4 u = *(const uint4*)(base + (size_t)c * 33280 + row * 256 + half * 2 + g * 16);
            a0[0] += bf2f(u.x & 0xffffu); a0[1] += bf2f(u.x >> 16);
            a0[2] += bf2f(u.y & 0xffffu); a0[3] += bf2f(u.y >> 16);
            a1[0] += bf2f(u.z & 0xffffu); a1[1] += bf2f(u.z >> 16);
            a1[2] += bf2f(u.w & 0xffffu); a1[3] += bf2f(u.w >> 16);
        }
        float4 r0, r1;
        r0.x=a0[0]*inv; r0.y=a0[1]*inv; r0.z=a0[2]*inv; r0.w=a0[3]*inv;
        r1.x=a1[0]*inv; r1.y=a1[1]*inv; r1.z=a1[2]*inv; r1.w=a1[3]*inv;
        *(float4*)(op + g * 8)     = r0;
        *(float4*)(op + g * 8 + 4) = r1;
    }
}

// ---------------- fallback (ws too small): round-3 proven kernel, no split ------
__global__ __launch_bounds__(256) void attn_fb(
    const float* __restrict__ Q, const float* __restrict__ K,
    const float* __restrict__ V, float* __restrict__ O)
{
    __shared__ __align__(16) unsigned short Klds[2][64 * 128];
    __shared__ __align__(16) unsigned short Vsh[2][128 * 64];
    __shared__ __align__(16) unsigned short Plds[4][16 * 64];

    const int qb = 31 - blockIdx.x;
    const int b  = blockIdx.y;
    const int ntile = qb + 1;
    const int tid  = threadIdx.x;
    const int lane = tid & 63;
    const int w    = tid >> 6;
    const int x    = lane & 15;
    const int hi   = lane >> 4;
    const int qrow0 = qb * 64 + w * 16;

    const float* qp    = Q + ((size_t)b * TT + qrow0) * DD;
    const float* kbase = K + (size_t)b * TT * DD;
    const float* vbase = V + (size_t)b * TT * DD;
    const float SCALE = 0.08838834764831845f;

    const int krow = tid >> 5;
    const int d4   = (tid & 31) * 4;
    const int dd   = tid & 127;
    const int g    = tid >> 7;

    bf16x8 qf[4];
    #pragma unroll
    for (int kc = 0; kc < 4; ++kc) {
        const float4* s0 = (const float4*)(qp + x * DD + kc * 32 + 8 * hi);
        float4 f0 = s0[0], f1 = s0[1];
        bf16x8 t;
        t[0]=(__bf16)f0.x; t[1]=(__bf16)f0.y; t[2]=(__bf16)f0.z; t[3]=(__bf16)f0.w;
        t[4]=(__bf16)f1.x; t[5]=(__bf16)f1.y; t[6]=(__bf16)f1.z; t[7]=(__bf16)f1.w;
        qf[kc] = t;
    }
    f32x4 o[8];
    #pragma unroll
    for (int nt = 0; nt < 8; ++nt) o[nt] = (f32x4){0.f,0.f,0.f,0.f};
    float lsum[4] = {0.f,0.f,0.f,0.f};
    float4 kreg[8];
    float  vreg[32];

    auto LOAD = [&](int t) {
        const float* kp = kbase + (size_t)(t * 64) * DD;
        const float* vp = vbase + (size_t)(t * 64) * DD;
        #pragma unroll
        for (int it = 0; it < 8; ++it)
            kreg[it] = *(const float4*)(kp + (size_t)(it * 8 + krow) * DD + d4);
        #pragma unroll
        for (int j = 0; j < 32; ++j)
            vreg[j] = vp[(size_t)(g * 32 + j) * DD + dd];
    };
    auto WRITE = [&](int buf) {
        char* kb8 = (char*)Klds[buf];
        #pragma unroll
        for (int it = 0; it < 8; ++it) {
            int key = it * 8 + krow;
            float4 f = kreg[it];
            bf16x4 h;
            h[0]=(__bf16)f.x; h[1]=(__bf16)f.y; h[2]=(__bf16)f.z; h[3]=(__bf16)f.w;
            *(bf16x4*)(kb8 + key * 256 + ((d4 * 2) ^ ((key & 7) << 4))) = h;
        }
        char* vb8 = (char*)Vsh[buf];
        #pragma unroll
        for (int m4 = 0; m4 < 4; ++m4) {
            bf16x8 h;
            #pragma unroll
            for (int j = 0; j < 8; ++j) h[j] = (__bf16)vreg[m4 * 8 + j];
            *(bf16x8*)(vb8 + dd * 128 + ((g * 64 + m4 * 16) ^ ((dd & 7) << 4))) = h;
        }
    };

    LOAD(0); WRITE(0);
    int cur = 0;
    char* pmine = (char*)Plds[w];

    for (int t = 0; t < ntile; ++t) {
        const int kb = t * 64;
        __syncthreads();
        if (t + 1 < ntile) LOAD(t + 1);

        const bool diag  = (t == qb);
        const int  ntmax = diag ? w : 3;
        const char* kb8  = (const char*)Klds[cur];
        float p[4][4];
        #pragma unroll
        for (int nt = 0; nt < 4; ++nt) {
            int key = nt * 16 + x;
            if (nt <= ntmax) {
                f32x4 acc = (f32x4){0.f,0.f,0.f,0.f};
                #pragma unroll
                for (int kc = 0; kc < 4; ++kc) {
                    int off = key * 256 + ((kc * 64 + 16 * hi) ^ ((key & 7) << 4));
                    bf16x8 bfr = *(const bf16x8*)(kb8 + off);
                    acc = __builtin_amdgcn_mfma_f32_16x16x32_bf16(qf[kc], bfr, acc, 0, 0, 0);
                }
                #pragma unroll
                for (int r = 0; r < 4; ++r) {
                    bool msk = diag && (kb + key > qrow0 + 4 * hi + r);
                    float pe = msk ? 0.f : __expf(acc[r] * SCALE);
                    p[nt][r] = pe;
                    lsum[r] += pe;
                }
            } else {
                #pragma unroll
                for (int r = 0; r < 4; ++r) p[nt][r] = 0.f;
            }
        }
        #pragma unroll
        for (int nt = 0; nt < 4; ++nt)
            #pragma unroll
            for (int r = 0; r < 4; ++r) {
                int q = 4 * hi + r;
                *(unsigned short*)(pmine + q * 128 + (((nt * 16 + x) * 2) ^ ((q & 7) << 4))) =
                    __builtin_bit_cast(unsigned short, (__bf16)p[nt][r]);
            }
        const char* vb8 = (const char*)Vsh[cur];
        #pragma unroll
        for (int kc = 0; kc < 2; ++kc) {
            bf16x8 af = *(const bf16x8*)(pmine + x * 128 + ((kc * 64 + 16 * hi) ^ ((x & 7) << 4)));
            #pragma unroll
            for (int nt = 0; nt < 8; ++nt) {
                int d = nt * 16 + x;
                bf16x8 bfr = *(const bf16x8*)(vb8 + d * 128 + ((kc * 64 + 16 * hi) ^ ((d & 7) << 4)));
                o[nt] = __builtin_amdgcn_mfma_f32_16x16x32_bf16(af, bfr, o[nt], 0, 0, 0);
            }
        }
        if (t + 1 < ntile) WRITE(cur ^ 1);
        cur ^= 1;
    }
    float* op = O + ((size_t)b * TT + qrow0) * DD;
    #pragma unroll
    for (int r = 0; r < 4; ++r) {
        float lr = warp16_sum(lsum[r]);
        float inv = 1.0f / lr;
        #pragma unroll
        for (int nt = 0; nt < 8; ++nt)
            op[(size_t)(4 * hi + r) * DD + nt * 16 + x] = o[nt][r] * inv;
    }
}

extern "C" void kernel_launch(void* const* d_in, const int* in_sizes, int n_in,
                              void* d_out, int out_size, void* d_ws, size_t ws_size,
                              hipStream_t stream) {
    const float* q = (const float*)d_in[0];
    const float* k = (const float*)d_in[1];
    const float* v = (const float*)d_in[2];
    float* out = (float*)d_out;

    const size_t PRE = (size_t)2 * NB * NTILE * TILE_BYTES;     // 16.78 MB
    auto slotsNeed = [](int QBMIN, int NCMAX) {
        return (size_t)(16 - QBMIN) * NB * NCMAX * 33280;
    };

    char* kb  = (char*)d_ws;
    char* vtb = kb + (size_t)NB * NTILE * TILE_BYTES;
    char* slots = vtb + (size_t)NB * NTILE * TILE_BYTES;

    if (ws_size >= PRE + slotsNeed(4, 4)) {            // ~42.3 MB
        prepass<<<dim3(NTILE, NB), 256, 0, stream>>>(k, v, kb, vtb);
        attn_main<<<dim3(NB, 16, 4), 256, 0, stream>>>(q, kb, vtb, out, slots, 8, 4, 4);
        attn_combine<<<dim3(12, NB), 256, 0, stream>>>(slots, out, 8, 4, 4);
    } else if (ws_size >= PRE + slotsNeed(8, 2)) {     // ~25.3 MB
        prepass<<<dim3(NTILE, NB), 256, 0, stream>>>(k, v, kb, vtb);
        attn_main<<<dim3(NB, 16, 2), 256, 0, stream>>>(q, kb, vtb, out, slots, 16, 2, 8);
        attn_combine<<<dim3(8, NB), 256, 0, stream>>>(slots, out, 16, 2, 8);
    } else if (ws_size >= PRE) {                       // 16.8 MB, no split
        prepass<<<dim3(NTILE, NB), 256, 0, stream>>>(k, v, kb, vtb);
        attn_main<<<dim3(NB, 16, 1), 256, 0, stream>>>(q, kb, vtb, out, slots, 32, 1, 16);
    } else {
        attn_fb<<<dim3(32, NB), 256, 0, stream>>>(q, k, v, out);
    }
}